// Round 4
// baseline (233.844 us; speedup 1.0000x reference)
//
#include <hip/hip_runtime.h>
#include <stdint.h>

typedef unsigned short u16;
typedef float v4f __attribute__((ext_vector_type(4)));
typedef short v8s __attribute__((ext_vector_type(8)));

#define B_   8192
#define IN_  1024
#define OUT_ 1024
#define D_   8

#define BM 128
#define BN 128
#define BK 64             // K-tile per phase: 32 MFMAs

__device__ __forceinline__ u16 f2bf(float f) {
  uint32_t u = __float_as_uint(f);
  u += 0x7fffu + ((u >> 16) & 1u);   // RTNE (inputs finite)
  return (u16)(u >> 16);
}

// v_cvt_pk_bf16_f32: two f32 -> packed 2x bf16 (RTNE), single VALU op.
__device__ __forceinline__ uint32_t cvtpk(float lo, float hi) {
  uint32_t r;
  asm("v_cvt_pk_bf16_f32 %0, %1, %2" : "=v"(r) : "v"(lo), "v"(hi));
  return r;
}

// ---- prep: weights f32 -> bf16 (32 MB read + 16 MB write) ------------------
__global__ __launch_bounds__(256) void convert_w(
    const float* __restrict__ weights, u16* __restrict__ wtBf) {
  const int i4 = blockIdx.x * 256 + threadIdx.x;
  float4 v = ((const float4*)weights)[i4];
  ushort4 o;
  o.x = f2bf(v.x); o.y = f2bf(v.y); o.z = f2bf(v.z); o.w = f2bf(v.w);
  ((ushort4*)wtBf)[i4] = o;
}

__device__ __forceinline__ void gload_lds16(const u16* g, u16* l) {
  typedef __attribute__((address_space(1))) void gvoid;
  typedef __attribute__((address_space(3))) void lvoid;
  __builtin_amdgcn_global_load_lds((gvoid*)g, (lvoid*)l, 16, 0, 0);
}

// ---- fused GEMM: counted-vmcnt 2-deep B pipeline (T3-min + T4) -------------
// R3 residuals fixed here:
//   (a) bx = XCD: each XCD's 64 blocks share ONE 2 MB B-stripe -> L2-resident
//       (R3 mapping streamed all 16 MB wtBf through each 4 MB L2).
//   (b) Bs triple-buffered; B-loads issued TWO phases ahead; phases end with
//       asm s_waitcnt vmcnt(4) lgkmcnt(0) + RAW s_barrier (never drain to 0
//       mid-loop; __syncthreads would force vmcnt(0) -> R3's 20% stall).
//   (c) A f32 prefetch at dd==6 (full-phase cover); dd==6 rescale runs BEFORE
//       the reload so one register set suffices (WAR handled by SSA).
//   (d) s_setprio(1) around the MFMA cluster (phase role-split now exists).
// vmcnt bookkeeping (verified): steady-state 4 B-loads in flight at barrier;
// dd==6 adds 8 A-loads -> vmcnt(12); t==126 -> vmcnt(0); t==127 no barrier.
__global__ __launch_bounds__(256, 2) void gemm_fused(
    const float* __restrict__ Ain,    // [B_][IN_] f32 input (unscaled)
    const u16* __restrict__ Wt,       // [D_][OUT_][IN_] bf16
    const float* __restrict__ w,      // [B_][D_]
    const float* __restrict__ biases, // [D_][OUT_]
    float* __restrict__ out) {        // [B_][OUT_]
  __shared__ __align__(16) u16 As[2][BM * BK];   // 32 KB
  __shared__ __align__(16) u16 Bs[3][BN * BK];   // 48 KB  (80 KB total: 2 blk/CU)

  const int id   = blockIdx.x;                // 512 blocks (2/CU)
  const int bx   = id & 7;                    // == XCD (dispatch round-robins id%8)
  const int by   = id >> 3;                   // 0..63

  const int tid  = threadIdx.x;
  const int wid  = tid >> 6;
  const int lane = tid & 63;
  const int wr   = wid >> 1, wc = wid & 1;
  const int quad = lane >> 4, l16 = lane & 15;
  const int m0   = by * BM;
  const int n0   = bx * BN;

  // staging geometry (proven): chunk c = wid*256+j*64+lane;
  // row = wid*32+j*8+(lane>>3); LDS chunk (lane&7) holds global chunk
  // swz = (lane&7)^(row&7); j-invariant.
  const int swz  = (lane & 7) ^ ((lane >> 3) & 7);
  const int rowS = wid * 32 + (lane >> 3);    // + j*8
  const float* aBase[4];
  const u16*   bBase[4];
  int cOff[4];                                // u16 offset within one buffer
#pragma unroll
  for (int j = 0; j < 4; ++j) {
    const int row = rowS + j * 8;
    aBase[j] = Ain + (size_t)(m0 + row) * IN_ + swz * 8;
    bBase[j] = Wt  + (size_t)(n0 + row) * IN_ + swz * 8;
    cOff[j]  = (wid * 256 + j * 64 + lane) * 8;
  }

  // per-row w[0..7] preloaded once (static-index select after unroll)
  float4 wA[4], wB[4];
#pragma unroll
  for (int j = 0; j < 4; ++j) {
    const float* wp = w + (size_t)(m0 + rowS + j * 8) * D_;
    wA[j] = ((const float4*)wp)[0];
    wB[j] = ((const float4*)wp)[1];
  }

  // fragment LDS offsets (u16 index), de-swizzled
  const int aRow = wr * 64 + l16;
  const int bRow = wc * 64 + l16;
  const int e    = l16 & 7;
  int aC[2];
#pragma unroll
  for (int h = 0; h < 2; ++h) aC[h] = ((quad + 4 * h) ^ e) * 8;

  const v4f vzero = {0.f, 0.f, 0.f, 0.f};
  v4f acc[4][4];
#pragma unroll
  for (int mt = 0; mt < 4; ++mt)
#pragma unroll
    for (int nt = 0; nt < 4; ++nt) acc[mt][nt] = vzero;

  // rotating B buffer pointers: compute(t) / next(t+1) / stage-target(t+2)
  u16* bC = Bs[0];
  u16* bN = Bs[1];
  u16* bS = Bs[2];

  float4 a0[4], a1[4];   // f32 A-chunk for the it whose phases are being staged

  // ---- prologue: A(it0) loads; B(t=0) -> bC, B(t=1) -> bN; stage As[0] (dd0)
#pragma unroll
  for (int j = 0; j < 4; ++j) {
    const float4* ap = (const float4*)aBase[j];
    a0[j] = ap[0]; a1[j] = ap[1];
  }
#pragma unroll
  for (int j = 0; j < 4; ++j) gload_lds16(bBase[j], bC + cOff[j]);
#pragma unroll
  for (int j = 0; j < 4; ++j)
    gload_lds16(bBase[j] + (size_t)(OUT_ * IN_), bN + cOff[j]);
#pragma unroll
  for (int j = 0; j < 4; ++j) {
    const float s = wA[j].x;   // dd = 0
    uint4 pk;
    pk.x = cvtpk(a0[j].x * s, a0[j].y * s);
    pk.y = cvtpk(a0[j].z * s, a0[j].w * s);
    pk.z = cvtpk(a1[j].x * s, a1[j].y * s);
    pk.w = cvtpk(a1[j].z * s, a1[j].w * s);
    *(uint4*)(&As[0][cOff[j]]) = pk;
  }
  asm volatile("s_waitcnt vmcnt(4) lgkmcnt(0)" ::: "memory");
  __builtin_amdgcn_s_barrier();

  // ---- main: t = it*8+dd, 128 phases
  for (int it = 0; it < IN_ / BK; ++it) {
#pragma unroll
    for (int dd = 0; dd < D_; ++dd) {
      const int cur = dd & 1;
      const int nxt = cur ^ 1;
      const bool lastPhase = (it == 15) && (dd == 7);

      // -- dd==6: stage (it,7) EARLY from current A regs (before reload)
      if (dd == 6) {
#pragma unroll
        for (int j = 0; j < 4; ++j) {
          const float s = wB[j].w;   // sdd = 7
          uint4 pk;
          pk.x = cvtpk(a0[j].x * s, a0[j].y * s);
          pk.y = cvtpk(a0[j].z * s, a0[j].w * s);
          pk.z = cvtpk(a1[j].x * s, a1[j].y * s);
          pk.w = cvtpk(a1[j].z * s, a1[j].w * s);
          *(uint4*)(&As[nxt][cOff[j]]) = pk;
        }
        if (it < 15) {               // A prefetch for it+1 (full-phase cover)
#pragma unroll
          for (int j = 0; j < 4; ++j) {
            const float4* ap = (const float4*)(aBase[j] + (it + 1) * BK);
            a0[j] = ap[0]; a1[j] = ap[1];
          }
        }
      }

      // -- issue B loads for phase t+2 into bS
      if (!((it == 15) && (dd >= 6))) {
        const int sdd2 = (dd <= 5) ? dd + 2 : dd - 6;   // 6->0, 7->1
        const int sit2 = (dd <= 5) ? it : it + 1;
#pragma unroll
        for (int j = 0; j < 4; ++j)
          gload_lds16(bBase[j] + (size_t)sdd2 * (OUT_ * IN_) + sit2 * BK,
                      bS + cOff[j]);
      }

      // -- compute on As[cur], bC
      __builtin_amdgcn_s_setprio(1);
#pragma unroll
      for (int h = 0; h < 2; ++h) {
        v8s af[4], bf[4];
#pragma unroll
        for (int mt = 0; mt < 4; ++mt)
          af[mt] = *(const v8s*)(&As[cur][(aRow + mt * 16) * BK + aC[h]]);
#pragma unroll
        for (int nt = 0; nt < 4; ++nt)
          bf[nt] = *(const v8s*)(bC + (bRow + nt * 16) * BK + aC[h]);
#pragma unroll
        for (int mt = 0; mt < 4; ++mt)
#pragma unroll
          for (int nt = 0; nt < 4; ++nt)
            acc[mt][nt] = __builtin_amdgcn_mfma_f32_16x16x32_bf16(
                af[mt], bf[nt], acc[mt][nt], 0, 0, 0);
      }
      __builtin_amdgcn_s_setprio(0);

      // -- write-late staging for the other phases (T14)
      if (dd != 6 && !lastPhase) {
        const int sdd = (dd + 1) & 7;   // dd==7 -> sdd=0, uses A(it+1) regs
#pragma unroll
        for (int j = 0; j < 4; ++j) {
          const float s = (sdd < 4) ? wA[j][sdd] : wB[j][sdd - 4];
          uint4 pk;
          pk.x = cvtpk(a0[j].x * s, a0[j].y * s);
          pk.y = cvtpk(a0[j].z * s, a0[j].w * s);
          pk.z = cvtpk(a1[j].x * s, a1[j].y * s);
          pk.w = cvtpk(a1[j].z * s, a1[j].w * s);
          *(uint4*)(&As[nxt][cOff[j]]) = pk;
        }
      }

      // -- counted wait + raw barrier (skip after final phase)
      if (!lastPhase) {
        if (dd == 6) {
          if (it < 15)
            asm volatile("s_waitcnt vmcnt(12) lgkmcnt(0)" ::: "memory");
          else
            asm volatile("s_waitcnt vmcnt(0) lgkmcnt(0)" ::: "memory");
        } else {
          asm volatile("s_waitcnt vmcnt(4) lgkmcnt(0)" ::: "memory");
        }
        __builtin_amdgcn_s_barrier();
      }

      // -- rotate B buffers
      u16* tmp = bC; bC = bN; bN = bS; bS = tmp;
    }
  }

  // ---- epilogue: add bias term sum_d w[b,d]*biases[d,o], plain stores
  float bcol[4][8];
#pragma unroll
  for (int nt = 0; nt < 4; ++nt) {
    const int col = n0 + wc * 64 + nt * 16 + l16;
#pragma unroll
    for (int dd = 0; dd < 8; ++dd) bcol[nt][dd] = biases[dd * OUT_ + col];
  }
#pragma unroll
  for (int mt = 0; mt < 4; ++mt) {
#pragma unroll
    for (int r = 0; r < 4; ++r) {
      const int grow = m0 + wr * 64 + mt * 16 + quad * 4 + r;
      const v4f* wp = (const v4f*)(w + (size_t)grow * D_);
      const v4f wa = wp[0], wb = wp[1];
#pragma unroll
      for (int nt = 0; nt < 4; ++nt) {
        const int col = n0 + wc * 64 + nt * 16 + l16;
        const float bias = wa[0] * bcol[nt][0] + wa[1] * bcol[nt][1] +
                           wa[2] * bcol[nt][2] + wa[3] * bcol[nt][3] +
                           wb[0] * bcol[nt][4] + wb[1] * bcol[nt][5] +
                           wb[2] * bcol[nt][6] + wb[3] * bcol[nt][7];
        out[(size_t)grow * OUT_ + col] = acc[mt][nt][r] + bias;
      }
    }
  }
}

extern "C" void kernel_launch(void* const* d_in, const int* in_sizes, int n_in,
                              void* d_out, int out_size, void* d_ws, size_t ws_size,
                              hipStream_t stream) {
  const float* input   = (const float*)d_in[0];
  const float* w       = (const float*)d_in[1];
  const float* weights = (const float*)d_in[2];
  const float* biases  = (const float*)d_in[3];
  float* out = (float*)d_out;

  u16* wtBf = (u16*)d_ws;                               // 16 MB

  const int nF4 = (D_ * OUT_ * IN_) / 4;                // one float4 / thread
  convert_w<<<dim3(nF4 / 256), 256, 0, stream>>>(weights, wtBf);
  gemm_fused<<<dim3(512), 256, 0, stream>>>(input, wtBf, w, biases, out);
}